// Round 1
// baseline (2459.847 us; speedup 1.0000x reference)
//
#include <hip/hip_runtime.h>
#include <cfloat>
#include <climits>
#include <cstdint>

// Problem constants
#define B_ 8
#define C_ 128
#define N_ 4096
#define OUT_ 256
#define K_ 16
#define NC_ 24          // candidate margin for exact fp64 re-rank
#define BN_ (B_ * N_)   // 32768

// ---------------------------------------------------------------------------
// K1: per-point squared norms (fp32) + transpose x (B,C,N) -> xt (B*N, C)
// so that later gathers read contiguous 512B rows.
// ---------------------------------------------------------------------------
__global__ __launch_bounds__(256) void k_sq_xt(const float* __restrict__ x,
                                               float* __restrict__ sq,
                                               float* __restrict__ xt) {
  const int b = blockIdx.x >> 6;
  const int n0 = (blockIdx.x & 63) << 6;
  __shared__ float xs[C_][64];   // 32 KB
  const float* xb = x + (size_t)b * C_ * N_;
  for (int id = threadIdx.x; id < C_ * 64; id += 256) {
    const int c = id >> 6, n = id & 63;
    xs[c][n] = xb[(size_t)c * N_ + n0 + n];
  }
  __syncthreads();
  if (threadIdx.x < 64) {
    const int n = threadIdx.x;
    float acc = 0.f;
#pragma unroll
    for (int c = 0; c < C_; ++c) { const float v = xs[c][n]; acc = fmaf(v, v, acc); }
    sq[b * N_ + n0 + n] = acc;
  }
  const int r = threadIdx.x >> 2;
  const int p = threadIdx.x & 3;
  float* dst = xt + ((size_t)(b * N_ + n0 + r)) * C_ + p * 32;
#pragma unroll
  for (int c0 = 0; c0 < 32; c0 += 4) {
    float4 o;
    o.x = xs[p * 32 + c0 + 0][r];
    o.y = xs[p * 32 + c0 + 1][r];
    o.z = xs[p * 32 + c0 + 2][r];
    o.w = xs[p * 32 + c0 + 3][r];
    *(float4*)(dst + c0) = o;
  }
}

// ---------------------------------------------------------------------------
// K2: tiled fp32 score GEMM + approximate top-NC candidate selection.
// Block = (batch, 64-row block). Iterates all 4096 columns in 64-col tiles.
// Score (within-row ordering only): s_j = 2*<x_i,x_j> - ||x_j||^2.
// Each thread owns (row = t&63, column-quarter = t>>6) and keeps a sorted
// top-16 list in registers (static indexing only). At the end the 4 lists
// per row are merged to the top-24 candidates (fp32).
// ---------------------------------------------------------------------------
__global__ __launch_bounds__(256, 2) void k_knn_cand(const float* __restrict__ x,
                                                     const float* __restrict__ sq,
                                                     int* __restrict__ cand) {
  const int b = blockIdx.x >> 6;
  const int i0 = (blockIdx.x & 63) << 6;
  union SMem {
    struct {
      float xr[C_][64];   // 32 KB row block (all K)
      float xc[32][64];   // 8 KB  column K-chunk
      float sc[64][68];   // 17.4 KB score tile (padded)
      float sqc[64];
    } s;
    struct {              // merge phase (reuses the space above)
      float mv[64][64];
      int   mi[64][64];
    } m;
  };
  __shared__ SMem sm;
  const int t = threadIdx.x;
  const float* xb = x + (size_t)b * C_ * N_;
  for (int id = t; id < C_ * 64; id += 256) {
    const int c = id >> 6, r = id & 63;
    sm.s.xr[c][r] = xb[(size_t)c * N_ + i0 + r];
  }
  float topv[K_];
  int topi[K_];
#pragma unroll
  for (int m = 0; m < K_; ++m) { topv[m] = -FLT_MAX; topi[m] = 0; }
  const int tx = t & 15, ty = t >> 4;
  const int myrow = t & 63, myq = t >> 6;

  for (int j0 = 0; j0 < N_; j0 += 64) {
    if (t < 64) sm.s.sqc[t] = sq[b * N_ + j0 + t];
    float acc[4][4] = {};
    for (int c0 = 0; c0 < C_; c0 += 32) {
      __syncthreads();
      for (int id = t; id < 32 * 64; id += 256) {
        const int c = id >> 6, j = id & 63;
        sm.s.xc[c][j] = xb[(size_t)(c0 + c) * N_ + j0 + j];
      }
      __syncthreads();
#pragma unroll 16
      for (int cc = 0; cc < 32; ++cc) {
        const float4 a = *(const float4*)&sm.s.xr[c0 + cc][ty * 4];
        const float4 w = *(const float4*)&sm.s.xc[cc][tx * 4];
        acc[0][0] = fmaf(a.x, w.x, acc[0][0]);
        acc[0][1] = fmaf(a.x, w.y, acc[0][1]);
        acc[0][2] = fmaf(a.x, w.z, acc[0][2]);
        acc[0][3] = fmaf(a.x, w.w, acc[0][3]);
        acc[1][0] = fmaf(a.y, w.x, acc[1][0]);
        acc[1][1] = fmaf(a.y, w.y, acc[1][1]);
        acc[1][2] = fmaf(a.y, w.z, acc[1][2]);
        acc[1][3] = fmaf(a.y, w.w, acc[1][3]);
        acc[2][0] = fmaf(a.z, w.x, acc[2][0]);
        acc[2][1] = fmaf(a.z, w.y, acc[2][1]);
        acc[2][2] = fmaf(a.z, w.z, acc[2][2]);
        acc[2][3] = fmaf(a.z, w.w, acc[2][3]);
        acc[3][0] = fmaf(a.w, w.x, acc[3][0]);
        acc[3][1] = fmaf(a.w, w.y, acc[3][1]);
        acc[3][2] = fmaf(a.w, w.z, acc[3][2]);
        acc[3][3] = fmaf(a.w, w.w, acc[3][3]);
      }
    }
    // write score tile (uses sqc, safe: chunk barriers above)
#pragma unroll
    for (int ri = 0; ri < 4; ++ri) {
#pragma unroll
      for (int ci = 0; ci < 4; ++ci) {
        sm.s.sc[ty * 4 + ri][tx * 4 + ci] =
            2.f * acc[ri][ci] - sm.s.sqc[tx * 4 + ci];
      }
    }
    __syncthreads();
    // owner scan: 16 scores of my (row, quarter)
    const int jbase = j0 + myq * 16;
#pragma unroll
    for (int u4 = 0; u4 < 4; ++u4) {
      const float4 sv = *(const float4*)&sm.s.sc[myrow][myq * 16 + u4 * 4];
      const float vs[4] = {sv.x, sv.y, sv.z, sv.w};
#pragma unroll
      for (int u = 0; u < 4; ++u) {
        float v = vs[u];
        if (v > topv[K_ - 1]) {
          int jj = jbase + u4 * 4 + u;
          bool ins = false;
#pragma unroll
          for (int m = 0; m < K_; ++m) {
            const bool sw = (v > topv[m]) || (ins && (v == topv[m]));
            const float tv = topv[m];
            const int ti = topi[m];
            if (sw) { topv[m] = v; topi[m] = jj; v = tv; jj = ti; ins = true; }
          }
        }
      }
    }
    // next tile's sqc/xc writes are protected by the barriers above
  }

  __syncthreads();
#pragma unroll
  for (int m = 0; m < K_; ++m) {
    sm.m.mv[myrow][myq * 16 + m] = topv[m];
    sm.m.mi[myrow][myq * 16 + m] = topi[m];
  }
  __syncthreads();
  if (t < 64) {
    int p0 = 0, p1 = 0, p2 = 0, p3 = 0;
    int* dst = cand + ((size_t)(b * N_ + i0 + t)) * NC_;
    for (int m = 0; m < NC_; ++m) {
      float bv = -FLT_MAX; int bi = INT_MAX; int bq = 0;
      {
        const bool ok = p0 < 16;
        const float v = ok ? sm.m.mv[t][0 * 16 + p0] : -FLT_MAX;
        const int ii = ok ? sm.m.mi[t][0 * 16 + p0] : INT_MAX;
        if (v > bv || (v == bv && ii < bi)) { bv = v; bi = ii; bq = 0; }
      }
      {
        const bool ok = p1 < 16;
        const float v = ok ? sm.m.mv[t][1 * 16 + p1] : -FLT_MAX;
        const int ii = ok ? sm.m.mi[t][1 * 16 + p1] : INT_MAX;
        if (v > bv || (v == bv && ii < bi)) { bv = v; bi = ii; bq = 1; }
      }
      {
        const bool ok = p2 < 16;
        const float v = ok ? sm.m.mv[t][2 * 16 + p2] : -FLT_MAX;
        const int ii = ok ? sm.m.mi[t][2 * 16 + p2] : INT_MAX;
        if (v > bv || (v == bv && ii < bi)) { bv = v; bi = ii; bq = 2; }
      }
      {
        const bool ok = p3 < 16;
        const float v = ok ? sm.m.mv[t][3 * 16 + p3] : -FLT_MAX;
        const int ii = ok ? sm.m.mi[t][3 * 16 + p3] : INT_MAX;
        if (v > bv || (v == bv && ii < bi)) { bv = v; bi = ii; bq = 3; }
      }
      dst[m] = bi;
      p0 += (bq == 0); p1 += (bq == 1); p2 += (bq == 2); p3 += (bq == 3);
    }
  }
}

// ---------------------------------------------------------------------------
// K2b: exact fp64 re-rank of the 24 candidates -> final top-16 indices.
// Half-wave (32 lanes) per row; lane l<24 computes exact squared distance.
// 16 rounds of butterfly arg-min (ties -> smaller index, matching top_k).
// ---------------------------------------------------------------------------
__global__ __launch_bounds__(256) void k_refine(const float* __restrict__ xt,
                                                const int* __restrict__ cand,
                                                int* __restrict__ knn) {
  const int half = threadIdx.x >> 5;              // 0..7
  const int l = threadIdx.x & 31;
  const int row = blockIdx.x * 8 + half;          // 0..32767
  const int b = row >> 12;
  const float4* xr4 = (const float4*)(xt + (size_t)row * C_);
  double d = DBL_MAX;
  int j = INT_MAX;
  if (l < NC_) {
    j = cand[(size_t)row * NC_ + l];
    const float4* xj4 = (const float4*)(xt + ((size_t)(b << 12) + j) * C_);
    double acc = 0.0;
#pragma unroll 8
    for (int c = 0; c < C_ / 4; ++c) {
      const float4 a = xr4[c];
      const float4 v = xj4[c];
      const double dx = (double)a.x - (double)v.x;
      const double dy = (double)a.y - (double)v.y;
      const double dz = (double)a.z - (double)v.z;
      const double dw = (double)a.w - (double)v.w;
      acc += dx * dx + dy * dy + dz * dz + dw * dw;
    }
    d = acc;
  }
  int* dst = knn + (size_t)row * K_;
  for (int m = 0; m < K_; ++m) {
    double bd = d; int bj = j;
#pragma unroll
    for (int off = 16; off > 0; off >>= 1) {
      const double od = __shfl_xor(bd, off, 32);
      const int oj = __shfl_xor(bj, off, 32);
      if (od < bd || (od == bd && oj < bj)) { bd = od; bj = oj; }
    }
    if (bj == j) d = DBL_MAX;   // exclude the winner on this lane
    if (l == 0) dst[m] = bj;
  }
}

// ---------------------------------------------------------------------------
// K3: gather + max-pool over 16 neighbors. One wave per output row; lane
// handles 2 channels (float2, 512B coalesced per neighbor row).
// ---------------------------------------------------------------------------
__global__ __launch_bounds__(256) void k_gather(const float* __restrict__ xt,
                                                const int* __restrict__ knn,
                                                float* __restrict__ pooled) {
  const int row = blockIdx.x * 4 + (threadIdx.x >> 6);
  const int lane = threadIdx.x & 63;
  const int b = row >> 12;
  const int* id = knn + (size_t)row * K_;
  float mx0 = -FLT_MAX, mx1 = -FLT_MAX;
#pragma unroll
  for (int m = 0; m < K_; ++m) {
    const int j = id[m];   // wave-uniform -> scalar load
    const float2 v = *(const float2*)&xt[((size_t)(b << 12) + j) * C_ + lane * 2];
    mx0 = fmaxf(mx0, v.x);
    mx1 = fmaxf(mx1, v.y);
  }
  float2 o; o.x = mx0; o.y = mx1;
  *(float2*)&pooled[(size_t)row * C_ + lane * 2] = o;
}

// ---------------------------------------------------------------------------
// K4: conv GEMM (stats pass). 64-row tile x 32-out chunks, micro 4x2.
// Accumulates per-channel sum / sumsq (incl. bias) into global via atomics.
// ---------------------------------------------------------------------------
__global__ __launch_bounds__(256, 2) void k_stats(const float* __restrict__ pooled,
                                                  const float* __restrict__ w,
                                                  const float* __restrict__ bias,
                                                  float* __restrict__ gsum,
                                                  float* __restrict__ gsumsq) {
  const int m0 = blockIdx.x << 6;
  __shared__ float pt[C_][68];   // 34.8 KB transposed pooled tile
  __shared__ float wt[C_][36];   // 18.4 KB transposed weight chunk
  __shared__ float bsum[32], bsq[32];
  const int t = threadIdx.x;
  for (int id = t; id < 64 * C_; id += 256) {
    const int row = id >> 7, c = id & 127;
    pt[c][row] = pooled[(size_t)(m0 + row) * C_ + c];
  }
  const int tx = t & 15, ty = t >> 4;
  for (int o0 = 0; o0 < OUT_; o0 += 32) {
    __syncthreads();
    for (int id = t; id < 32 * C_; id += 256) {
      const int oo = id >> 7, c = id & 127;
      wt[c][oo] = w[(size_t)(o0 + oo) * C_ + c];
    }
    if (t < 32) { bsum[t] = 0.f; bsq[t] = 0.f; }
    __syncthreads();
    float acc[4][2] = {};
#pragma unroll 8
    for (int cc = 0; cc < C_; ++cc) {
      const float4 a = *(const float4*)&pt[cc][ty * 4];
      const float2 wv = *(const float2*)&wt[cc][tx * 2];
      acc[0][0] = fmaf(a.x, wv.x, acc[0][0]);
      acc[0][1] = fmaf(a.x, wv.y, acc[0][1]);
      acc[1][0] = fmaf(a.y, wv.x, acc[1][0]);
      acc[1][1] = fmaf(a.y, wv.y, acc[1][1]);
      acc[2][0] = fmaf(a.z, wv.x, acc[2][0]);
      acc[2][1] = fmaf(a.z, wv.y, acc[2][1]);
      acc[3][0] = fmaf(a.w, wv.x, acc[3][0]);
      acc[3][1] = fmaf(a.w, wv.y, acc[3][1]);
    }
#pragma unroll
    for (int ci = 0; ci < 2; ++ci) {
      const float bi = bias[o0 + tx * 2 + ci];
      float s = 0.f, q = 0.f;
#pragma unroll
      for (int ri = 0; ri < 4; ++ri) {
        const float y = acc[ri][ci] + bi;
        s += y;
        q = fmaf(y, y, q);
      }
      atomicAdd(&bsum[tx * 2 + ci], s);
      atomicAdd(&bsq[tx * 2 + ci], q);
    }
    __syncthreads();
    if (t < 32) {
      atomicAdd(&gsum[o0 + t], bsum[t]);
      atomicAdd(&gsumsq[o0 + t], bsq[t]);
    }
  }
}

// ---------------------------------------------------------------------------
// K5: conv GEMM again + fused BN(train) + ReLU + transposed store (B,OUT,N).
// ---------------------------------------------------------------------------
__global__ __launch_bounds__(256, 2) void k_norm(const float* __restrict__ pooled,
                                                 const float* __restrict__ w,
                                                 const float* __restrict__ bias,
                                                 const float* __restrict__ gamma,
                                                 const float* __restrict__ beta,
                                                 const float* __restrict__ gsum,
                                                 const float* __restrict__ gsumsq,
                                                 float* __restrict__ out) {
  const int m0 = blockIdx.x << 6;
  const int b = m0 >> 12;
  const int n0 = m0 & (N_ - 1);
  __shared__ float pt[C_][68];
  __shared__ float wt[C_][36];
  __shared__ float sscale[32], sshift[32];
  const int t = threadIdx.x;
  for (int id = t; id < 64 * C_; id += 256) {
    const int row = id >> 7, c = id & 127;
    pt[c][row] = pooled[(size_t)(m0 + row) * C_ + c];
  }
  const int tx = t & 15, ty = t >> 4;
  const float inv = 1.f / (float)BN_;
  for (int o0 = 0; o0 < OUT_; o0 += 32) {
    __syncthreads();
    for (int id = t; id < 32 * C_; id += 256) {
      const int oo = id >> 7, c = id & 127;
      wt[c][oo] = w[(size_t)(o0 + oo) * C_ + c];
    }
    if (t < 32) {
      const int o = o0 + t;
      const float mean = gsum[o] * inv;
      const float var = gsumsq[o] * inv - mean * mean;
      const float sc = gamma[o] / sqrtf(var + 1e-5f);
      sscale[t] = sc;
      sshift[t] = (bias[o] - mean) * sc + beta[o];
    }
    __syncthreads();
    float acc[4][2] = {};
#pragma unroll 8
    for (int cc = 0; cc < C_; ++cc) {
      const float4 a = *(const float4*)&pt[cc][ty * 4];
      const float2 wv = *(const float2*)&wt[cc][tx * 2];
      acc[0][0] = fmaf(a.x, wv.x, acc[0][0]);
      acc[0][1] = fmaf(a.x, wv.y, acc[0][1]);
      acc[1][0] = fmaf(a.y, wv.x, acc[1][0]);
      acc[1][1] = fmaf(a.y, wv.y, acc[1][1]);
      acc[2][0] = fmaf(a.z, wv.x, acc[2][0]);
      acc[2][1] = fmaf(a.z, wv.y, acc[2][1]);
      acc[3][0] = fmaf(a.w, wv.x, acc[3][0]);
      acc[3][1] = fmaf(a.w, wv.y, acc[3][1]);
    }
#pragma unroll
    for (int ci = 0; ci < 2; ++ci) {
      const int o = o0 + tx * 2 + ci;
      const float scl = sscale[tx * 2 + ci];
      const float sh = sshift[tx * 2 + ci];
      float4 r;
      r.x = fmaxf(fmaf(acc[0][ci], scl, sh), 0.f);
      r.y = fmaxf(fmaf(acc[1][ci], scl, sh), 0.f);
      r.z = fmaxf(fmaf(acc[2][ci], scl, sh), 0.f);
      r.w = fmaxf(fmaf(acc[3][ci], scl, sh), 0.f);
      *(float4*)&out[((size_t)(b * OUT_ + o)) * N_ + n0 + ty * 4] = r;
    }
  }
}

// ---------------------------------------------------------------------------
// Launcher. ws layout (floats):
//   sq[32768] | xt[32768*128] | knn[32768*16](int) | cand[32768*24](int)
//   | pooled[32768*128] | gsum[256] | gsumsq[256]   (~37.1 MB total)
// ---------------------------------------------------------------------------
extern "C" void kernel_launch(void* const* d_in, const int* in_sizes, int n_in,
                              void* d_out, int out_size, void* d_ws, size_t ws_size,
                              hipStream_t stream) {
  const float* x      = (const float*)d_in[0];
  const float* conv_w = (const float*)d_in[1];
  const float* conv_b = (const float*)d_in[2];
  const float* gamma  = (const float*)d_in[3];
  const float* beta   = (const float*)d_in[4];
  float* out = (float*)d_out;

  float* ws = (float*)d_ws;
  float* sq = ws;                                        // 32768
  float* xt = sq + BN_;                                  // 4194304
  int*   knn = (int*)(xt + (size_t)BN_ * C_);            // 524288
  int*   cand = knn + (size_t)BN_ * K_;                  // 786432
  float* pooled = (float*)(cand + (size_t)BN_ * NC_);    // 4194304
  float* gsum = pooled + (size_t)BN_ * C_;               // 256
  float* gsumsq = gsum + OUT_;                           // 256

  hipMemsetAsync(gsum, 0, 2 * OUT_ * sizeof(float), stream);

  k_sq_xt<<<B_ * (N_ / 64), 256, 0, stream>>>(x, sq, xt);
  k_knn_cand<<<B_ * (N_ / 64), 256, 0, stream>>>(x, sq, cand);
  k_refine<<<BN_ / 8, 256, 0, stream>>>(xt, cand, knn);
  k_gather<<<BN_ / 4, 256, 0, stream>>>(xt, knn, pooled);
  k_stats<<<BN_ / 64, 256, 0, stream>>>(pooled, conv_w, conv_b, gsum, gsumsq);
  k_norm<<<BN_ / 64, 256, 0, stream>>>(pooled, conv_w, conv_b, gamma, beta,
                                       gsum, gsumsq, out);
}

// Round 2
// 1500.253 us; speedup vs baseline: 1.6396x; 1.6396x over previous
//
#include <hip/hip_runtime.h>
#include <cfloat>
#include <climits>
#include <cstdint>

// Problem constants
#define B_ 8
#define C_ 128
#define N_ 4096
#define OUT_ 256
#define K_ 16
#define NC_ 24          // candidate margin for exact fp64 re-rank
#define BN_ (B_ * N_)   // 32768

typedef __attribute__((ext_vector_type(8))) short s16x8;
typedef __attribute__((ext_vector_type(16))) float f32x16;

static __device__ __forceinline__ ushort f2bf(float f) {
  uint32_t u = __float_as_uint(f);
  uint32_t r = (u + 0x7fffu + ((u >> 16) & 1u)) >> 16;
  return (ushort)r;
}

// ---------------------------------------------------------------------------
// K1: per-point squared norms (fp32) + transpose x (B,C,N) -> xt (B*N, C) f32
// and xb16 (B*N, C) bf16 (row-major, 256B rows) for the MFMA scorer.
// ---------------------------------------------------------------------------
__global__ __launch_bounds__(256) void k_sq_xt(const float* __restrict__ x,
                                               float* __restrict__ sq,
                                               float* __restrict__ xt,
                                               ushort* __restrict__ xb16) {
  const int b = blockIdx.x >> 6;
  const int n0 = (blockIdx.x & 63) << 6;
  __shared__ float xs[C_][65];   // +1 pad: breaks transpose-read conflicts
  const float* xb = x + (size_t)b * C_ * N_;
  for (int id = threadIdx.x; id < C_ * 64; id += 256) {
    const int c = id >> 6, n = id & 63;
    xs[c][n] = xb[(size_t)c * N_ + n0 + n];
  }
  __syncthreads();
  if (threadIdx.x < 64) {
    const int n = threadIdx.x;
    float acc = 0.f;
#pragma unroll
    for (int c = 0; c < C_; ++c) { const float v = xs[c][n]; acc = fmaf(v, v, acc); }
    sq[b * N_ + n0 + n] = acc;
  }
  const int r = threadIdx.x >> 2;
  const int p = threadIdx.x & 3;
  float* dst = xt + ((size_t)(b * N_ + n0 + r)) * C_ + p * 32;
#pragma unroll
  for (int c0 = 0; c0 < 32; c0 += 4) {
    float4 o;
    o.x = xs[p * 32 + c0 + 0][r];
    o.y = xs[p * 32 + c0 + 1][r];
    o.z = xs[p * 32 + c0 + 2][r];
    o.w = xs[p * 32 + c0 + 3][r];
    *(float4*)(dst + c0) = o;
  }
  ushort* bdst = xb16 + ((size_t)(b * N_ + n0 + r)) * C_ + p * 32;
#pragma unroll
  for (int c0 = 0; c0 < 32; c0 += 8) {
    s16x8 o;
#pragma unroll
    for (int e = 0; e < 8; ++e) o[e] = (short)f2bf(xs[p * 32 + c0 + e][r]);
    *(s16x8*)(bdst + c0) = o;
  }
}

// ---------------------------------------------------------------------------
// K2: bf16 MFMA score GEMM + per-lane register top-16 selection.
// Block = (batch, 64-row block), 4 waves. Each wave: I-fragments (64 rows,
// 2 col-frags of 32) in registers; scans its private 1024-col j-quarter in
// 32-col tiles staged to wave-private double-buffered LDS via
// global_load_lds(16B) with XOR-16-slot swizzle (pre-swizzled global source,
// swizzled ds_read_b128 — rule 21 compliant). Score = <xi,xj> - sq_j/2
// (monotone-equivalent ordering), with -sq_j/2 folded into MFMA C-in.
// Per-(lane,col-frag) sorted top-16 lists; 8-way merge -> top-24 candidates.
// ---------------------------------------------------------------------------
__global__ __launch_bounds__(256, 2) void k_knn_mfma(
    const ushort* __restrict__ xb16, const float* __restrict__ sq,
    int* __restrict__ cand) {
  const int b  = blockIdx.x >> 6;
  const int i0 = (blockIdx.x & 63) << 6;
  const int t  = threadIdx.x;
  const int w  = t >> 6;          // wave 0..3
  const int lane = t & 63;
  const int li = lane & 31;
  const int kh = lane >> 5;       // k-half / j-subclass

  __shared__ ushort jbuf[4][2][32 * C_];   // 4 waves x dbuf x 8KB = 64 KB

  const ushort* xbB = xb16 + (((size_t)b) << 12) * C_;
  const float* sqB = sq + (b << 12);

  // I fragments: B-operand, col = li, k = kh*8 + e within each 16-k step.
  s16x8 bfr[2][8];
#pragma unroll
  for (int c = 0; c < 2; ++c) {
    const ushort* ip = xbB + ((size_t)(i0 + c * 32 + li)) * C_ + kh * 8;
#pragma unroll
    for (int s = 0; s < 8; ++s) bfr[c][s] = *(const s16x8*)(ip + s * 16);
  }

  const int jq0 = w << 10;        // wave's 1024-col quarter
  const int st_jl = lane >> 4;    // staging: local row offset
  const int st_s  = lane & 15;    // staging: 16B slot

  float topv0[K_], topv1[K_];
  int topi0[K_], topi1[K_];
#pragma unroll
  for (int m = 0; m < K_; ++m) {
    topv0[m] = -FLT_MAX; topv1[m] = -FLT_MAX; topi0[m] = 0; topi1[m] = 0;
  }

  float sqa[16], sqan[16];

  // stage(buf, js): 8 x global_load_lds(16B); dest linear, source pre-swizzled
  auto stage = [&](int buf, int js) {
#pragma unroll
    for (int it = 0; it < 8; ++it) {
      const int jl = it * 4 + st_jl;
      const int chunk = st_s ^ (jl & 15);
      const ushort* gsrc = xbB + ((size_t)(js + jl)) * C_ + chunk * 8;
      __builtin_amdgcn_global_load_lds(
          (const __attribute__((address_space(1))) void*)gsrc,
          (__attribute__((address_space(3))) void*)&jbuf[w][buf][it * 4 * C_],
          16, 0, 0);
    }
  };
  auto load_sq = [&](int js, float* dst) {
    const float* sp = sqB + js + kh * 4;
#pragma unroll
    for (int q = 0; q < 4; ++q) {
      const float4 v = *(const float4*)(sp + q * 8);
      dst[q * 4 + 0] = v.x; dst[q * 4 + 1] = v.y;
      dst[q * 4 + 2] = v.z; dst[q * 4 + 3] = v.w;
    }
  };

  stage(0, jq0);
  load_sq(jq0, sqa);

  for (int jt = 0; jt < 32; ++jt) {
    // tile jt's staging (issued last iteration or prologue) completes here;
    // next tile's loads below overlap this tile's compute.
    asm volatile("s_waitcnt vmcnt(0)" ::: "memory");
    if (jt + 1 < 32) {
      stage((jt + 1) & 1, jq0 + (jt + 1) * 32);
      load_sq(jq0 + (jt + 1) * 32, sqan);
    }

    f32x16 initv;
#pragma unroll
    for (int r = 0; r < 16; ++r) initv[r] = -0.5f * sqa[r];

    const ushort* jbw = &jbuf[w][jt & 1][0];
    f32x16 acc0, acc1;
#pragma unroll
    for (int ks = 0; ks < 8; ++ks) {
      const int slot = (2 * ks + kh) ^ (li & 15);
      const s16x8 a = *(const s16x8*)&jbw[li * C_ + slot * 8];
      if (ks == 0) {
        acc0 = __builtin_amdgcn_mfma_f32_32x32x16_bf16(a, bfr[0][0], initv, 0, 0, 0);
        acc1 = __builtin_amdgcn_mfma_f32_32x32x16_bf16(a, bfr[1][0], initv, 0, 0, 0);
      } else {
        acc0 = __builtin_amdgcn_mfma_f32_32x32x16_bf16(a, bfr[0][ks], acc0, 0, 0, 0);
        acc1 = __builtin_amdgcn_mfma_f32_32x32x16_bf16(a, bfr[1][ks], acc1, 0, 0, 0);
      }
    }

    // selection: lane holds j = js + (r&3) + 8*(r>>2) + 4*kh per reg r,
    // for i = i0 + li (acc0) and i0 + 32 + li (acc1).
    const int jb0 = jq0 + jt * 32 + 4 * kh;
#pragma unroll
    for (int r = 0; r < 16; ++r) {
      const int jj0 = jb0 + (r & 3) + 8 * (r >> 2);
      {
        float v = acc0[r];
        if (v > topv0[K_ - 1]) {
          int jj = jj0; bool ins = false;
#pragma unroll
          for (int m = 0; m < K_; ++m) {
            const bool sw = (v > topv0[m]) || (ins && (v == topv0[m]));
            const float tv = topv0[m]; const int ti = topi0[m];
            if (sw) { topv0[m] = v; topi0[m] = jj; v = tv; jj = ti; ins = true; }
          }
        }
      }
      {
        float v = acc1[r];
        if (v > topv1[K_ - 1]) {
          int jj = jj0; bool ins = false;
#pragma unroll
          for (int m = 0; m < K_; ++m) {
            const bool sw = (v > topv1[m]) || (ins && (v == topv1[m]));
            const float tv = topv1[m]; const int ti = topi1[m];
            if (sw) { topv1[m] = v; topi1[m] = jj; v = tv; jj = ti; ins = true; }
          }
        }
      }
    }
    if (jt + 1 < 32) {
#pragma unroll
      for (int q = 0; q < 16; ++q) sqa[q] = sqan[q];
    }
  }

  // ---- merge phase (aliases jbuf after all waves are done with it) ----
  __syncthreads();
  float* mv = (float*)&jbuf[0][0][0];          // [64][128] f32 = 32 KB
  int*   mi = (int*)(mv + 64 * 128);           // [64][128] i32 = 32 KB
  const int listid = w * 2 + kh;               // 0..7
#pragma unroll
  for (int m = 0; m < K_; ++m) {
    mv[li * 128 + listid * 16 + m] = topv0[m];
    mi[li * 128 + listid * 16 + m] = topi0[m];
    mv[(li + 32) * 128 + listid * 16 + m] = topv1[m];
    mi[(li + 32) * 128 + listid * 16 + m] = topi1[m];
  }
  __syncthreads();

  if (t < 64) {
    const float* lv = &mv[t * 128];
    const int* lx = &mi[t * 128];
    unsigned long long pp = 0;  // 8 x 8-bit list cursors (avoids scratch)
    int* dst = cand + ((size_t)((b << 12) + i0 + t)) * NC_;
    for (int m = 0; m < NC_; ++m) {
      float bv = -FLT_MAX; int bi = INT_MAX; int bl = 0;
#pragma unroll
      for (int l = 0; l < 8; ++l) {
        const int pl = (int)((pp >> (l * 8)) & 0xff);
        const bool ok = pl < K_;
        const float v = ok ? lv[l * 16 + pl] : -FLT_MAX;
        const int ii = ok ? lx[l * 16 + pl] : INT_MAX;
        if (v > bv || (v == bv && ii < bi)) { bv = v; bi = ii; bl = l; }
      }
      dst[m] = bi;
      pp += 1ull << (bl * 8);
    }
  }
}

// ---------------------------------------------------------------------------
// K2b: exact fp64 re-rank of the 24 candidates -> final top-16 indices.
// ---------------------------------------------------------------------------
__global__ __launch_bounds__(256) void k_refine(const float* __restrict__ xt,
                                                const int* __restrict__ cand,
                                                int* __restrict__ knn) {
  const int half = threadIdx.x >> 5;
  const int l = threadIdx.x & 31;
  const int row = blockIdx.x * 8 + half;
  const int b = row >> 12;
  const float4* xr4 = (const float4*)(xt + (size_t)row * C_);
  double d = DBL_MAX;
  int j = INT_MAX;
  if (l < NC_) {
    j = cand[(size_t)row * NC_ + l];
    const float4* xj4 = (const float4*)(xt + ((size_t)(b << 12) + j) * C_);
    double acc = 0.0;
#pragma unroll 8
    for (int c = 0; c < C_ / 4; ++c) {
      const float4 a = xr4[c];
      const float4 v = xj4[c];
      const double dx = (double)a.x - (double)v.x;
      const double dy = (double)a.y - (double)v.y;
      const double dz = (double)a.z - (double)v.z;
      const double dw = (double)a.w - (double)v.w;
      acc += dx * dx + dy * dy + dz * dz + dw * dw;
    }
    d = acc;
  }
  int* dst = knn + (size_t)row * K_;
  for (int m = 0; m < K_; ++m) {
    double bd = d; int bj = j;
#pragma unroll
    for (int off = 16; off > 0; off >>= 1) {
      const double od = __shfl_xor(bd, off, 32);
      const int oj = __shfl_xor(bj, off, 32);
      if (od < bd || (od == bd && oj < bj)) { bd = od; bj = oj; }
    }
    if (bj == j) d = DBL_MAX;
    if (l == 0) dst[m] = bj;
  }
}

// ---------------------------------------------------------------------------
// K3: gather + max-pool over 16 neighbors.
// ---------------------------------------------------------------------------
__global__ __launch_bounds__(256) void k_gather(const float* __restrict__ xt,
                                                const int* __restrict__ knn,
                                                float* __restrict__ pooled) {
  const int row = blockIdx.x * 4 + (threadIdx.x >> 6);
  const int lane = threadIdx.x & 63;
  const int b = row >> 12;
  const int* id = knn + (size_t)row * K_;
  float mx0 = -FLT_MAX, mx1 = -FLT_MAX;
#pragma unroll
  for (int m = 0; m < K_; ++m) {
    const int j = id[m];
    const float2 v = *(const float2*)&xt[((size_t)(b << 12) + j) * C_ + lane * 2];
    mx0 = fmaxf(mx0, v.x);
    mx1 = fmaxf(mx1, v.y);
  }
  float2 o; o.x = mx0; o.y = mx1;
  *(float2*)&pooled[(size_t)row * C_ + lane * 2] = o;
}

// ---------------------------------------------------------------------------
// K4: conv GEMM (stats pass) -> per-channel sum / sumsq.
// ---------------------------------------------------------------------------
__global__ __launch_bounds__(256, 2) void k_stats(const float* __restrict__ pooled,
                                                  const float* __restrict__ w,
                                                  const float* __restrict__ bias,
                                                  float* __restrict__ gsum,
                                                  float* __restrict__ gsumsq) {
  const int m0 = blockIdx.x << 6;
  __shared__ float pt[C_][68];
  __shared__ float wt[C_][36];
  __shared__ float bsum[32], bsq[32];
  const int t = threadIdx.x;
  for (int id = t; id < 64 * C_; id += 256) {
    const int row = id >> 7, c = id & 127;
    pt[c][row] = pooled[(size_t)(m0 + row) * C_ + c];
  }
  const int tx = t & 15, ty = t >> 4;
  for (int o0 = 0; o0 < OUT_; o0 += 32) {
    __syncthreads();
    for (int id = t; id < 32 * C_; id += 256) {
      const int oo = id >> 7, c = id & 127;
      wt[c][oo] = w[(size_t)(o0 + oo) * C_ + c];
    }
    if (t < 32) { bsum[t] = 0.f; bsq[t] = 0.f; }
    __syncthreads();
    float acc[4][2] = {};
#pragma unroll 8
    for (int cc = 0; cc < C_; ++cc) {
      const float4 a = *(const float4*)&pt[cc][ty * 4];
      const float2 wv = *(const float2*)&wt[cc][tx * 2];
      acc[0][0] = fmaf(a.x, wv.x, acc[0][0]);
      acc[0][1] = fmaf(a.x, wv.y, acc[0][1]);
      acc[1][0] = fmaf(a.y, wv.x, acc[1][0]);
      acc[1][1] = fmaf(a.y, wv.y, acc[1][1]);
      acc[2][0] = fmaf(a.z, wv.x, acc[2][0]);
      acc[2][1] = fmaf(a.z, wv.y, acc[2][1]);
      acc[3][0] = fmaf(a.w, wv.x, acc[3][0]);
      acc[3][1] = fmaf(a.w, wv.y, acc[3][1]);
    }
#pragma unroll
    for (int ci = 0; ci < 2; ++ci) {
      const float bi = bias[o0 + tx * 2 + ci];
      float s = 0.f, q = 0.f;
#pragma unroll
      for (int ri = 0; ri < 4; ++ri) {
        const float y = acc[ri][ci] + bi;
        s += y;
        q = fmaf(y, y, q);
      }
      atomicAdd(&bsum[tx * 2 + ci], s);
      atomicAdd(&bsq[tx * 2 + ci], q);
    }
    __syncthreads();
    if (t < 32) {
      atomicAdd(&gsum[o0 + t], bsum[t]);
      atomicAdd(&gsumsq[o0 + t], bsq[t]);
    }
  }
}

// ---------------------------------------------------------------------------
// K5: conv GEMM again + fused BN(train) + ReLU + transposed store (B,OUT,N).
// ---------------------------------------------------------------------------
__global__ __launch_bounds__(256, 2) void k_norm(const float* __restrict__ pooled,
                                                 const float* __restrict__ w,
                                                 const float* __restrict__ bias,
                                                 const float* __restrict__ gamma,
                                                 const float* __restrict__ beta,
                                                 const float* __restrict__ gsum,
                                                 const float* __restrict__ gsumsq,
                                                 float* __restrict__ out) {
  const int m0 = blockIdx.x << 6;
  const int b = m0 >> 12;
  const int n0 = m0 & (N_ - 1);
  __shared__ float pt[C_][68];
  __shared__ float wt[C_][36];
  __shared__ float sscale[32], sshift[32];
  const int t = threadIdx.x;
  for (int id = t; id < 64 * C_; id += 256) {
    const int row = id >> 7, c = id & 127;
    pt[c][row] = pooled[(size_t)(m0 + row) * C_ + c];
  }
  const int tx = t & 15, ty = t >> 4;
  const float inv = 1.f / (float)BN_;
  for (int o0 = 0; o0 < OUT_; o0 += 32) {
    __syncthreads();
    for (int id = t; id < 32 * C_; id += 256) {
      const int oo = id >> 7, c = id & 127;
      wt[c][oo] = w[(size_t)(o0 + oo) * C_ + c];
    }
    if (t < 32) {
      const int o = o0 + t;
      const float mean = gsum[o] * inv;
      const float var = gsumsq[o] * inv - mean * mean;
      const float sc = gamma[o] / sqrtf(var + 1e-5f);
      sscale[t] = sc;
      sshift[t] = (bias[o] - mean) * sc + beta[o];
    }
    __syncthreads();
    float acc[4][2] = {};
#pragma unroll 8
    for (int cc = 0; cc < C_; ++cc) {
      const float4 a = *(const float4*)&pt[cc][ty * 4];
      const float2 wv = *(const float2*)&wt[cc][tx * 2];
      acc[0][0] = fmaf(a.x, wv.x, acc[0][0]);
      acc[0][1] = fmaf(a.x, wv.y, acc[0][1]);
      acc[1][0] = fmaf(a.y, wv.x, acc[1][0]);
      acc[1][1] = fmaf(a.y, wv.y, acc[1][1]);
      acc[2][0] = fmaf(a.z, wv.x, acc[2][0]);
      acc[2][1] = fmaf(a.z, wv.y, acc[2][1]);
      acc[3][0] = fmaf(a.w, wv.x, acc[3][0]);
      acc[3][1] = fmaf(a.w, wv.y, acc[3][1]);
    }
#pragma unroll
    for (int ci = 0; ci < 2; ++ci) {
      const int o = o0 + tx * 2 + ci;
      const float scl = sscale[tx * 2 + ci];
      const float sh = sshift[tx * 2 + ci];
      float4 r;
      r.x = fmaxf(fmaf(acc[0][ci], scl, sh), 0.f);
      r.y = fmaxf(fmaf(acc[1][ci], scl, sh), 0.f);
      r.z = fmaxf(fmaf(acc[2][ci], scl, sh), 0.f);
      r.w = fmaxf(fmaf(acc[3][ci], scl, sh), 0.f);
      *(float4*)&out[((size_t)(b * OUT_ + o)) * N_ + n0 + ty * 4] = r;
    }
  }
}

// ---------------------------------------------------------------------------
// Launcher. ws layout (floats):
//   sq[32768] | xt[32768*128] | knn(int) | cand(int) | pooled | gsum | gsumsq
//   | xb16[32768*128] bf16   (~45.5 MB total)
// ---------------------------------------------------------------------------
extern "C" void kernel_launch(void* const* d_in, const int* in_sizes, int n_in,
                              void* d_out, int out_size, void* d_ws, size_t ws_size,
                              hipStream_t stream) {
  const float* x      = (const float*)d_in[0];
  const float* conv_w = (const float*)d_in[1];
  const float* conv_b = (const float*)d_in[2];
  const float* gamma  = (const float*)d_in[3];
  const float* beta   = (const float*)d_in[4];
  float* out = (float*)d_out;

  float* ws = (float*)d_ws;
  float* sq = ws;                                        // 32768
  float* xt = sq + BN_;                                  // 4194304
  int*   knn = (int*)(xt + (size_t)BN_ * C_);            // 524288
  int*   cand = knn + (size_t)BN_ * K_;                  // 786432
  float* pooled = (float*)(cand + (size_t)BN_ * NC_);    // 4194304
  float* gsum = pooled + (size_t)BN_ * C_;               // 256
  float* gsumsq = gsum + OUT_;                           // 256
  ushort* xb16 = (ushort*)(gsumsq + OUT_);               // 4194304 bf16

  hipMemsetAsync(gsum, 0, 2 * OUT_ * sizeof(float), stream);

  k_sq_xt<<<B_ * (N_ / 64), 256, 0, stream>>>(x, sq, xt, xb16);
  k_knn_mfma<<<B_ * (N_ / 64), 256, 0, stream>>>(xb16, sq, cand);
  k_refine<<<BN_ / 8, 256, 0, stream>>>(xt, cand, knn);
  k_gather<<<BN_ / 4, 256, 0, stream>>>(xt, knn, pooled);
  k_stats<<<BN_ / 64, 256, 0, stream>>>(pooled, conv_w, conv_b, gsum, gsumsq);
  k_norm<<<BN_ / 64, 256, 0, stream>>>(pooled, conv_w, conv_b, gamma, beta,
                                       gsum, gsumsq, out);
}

// Round 3
// 441.398 us; speedup vs baseline: 5.5729x; 3.3989x over previous
//
#include <hip/hip_runtime.h>
#include <cfloat>
#include <climits>
#include <cstdint>

// Problem constants
#define B_ 8
#define C_ 128
#define N_ 4096
#define OUT_ 256
#define K_ 16
#define NC_ 24          // candidate margin for exact fp64 re-rank
#define BN_ (B_ * N_)   // 32768
#define SBIAS 200.0f    // score bias: keeps packed scores positive (s' > -195 w.h.p.)

typedef __attribute__((ext_vector_type(8))) short s16x8;
typedef __attribute__((ext_vector_type(16))) float f32x16;

static __device__ __forceinline__ ushort f2bf(float f) {
  uint32_t u = __float_as_uint(f);
  uint32_t r = (u + 0x7fffu + ((u >> 16) & 1u)) >> 16;
  return (ushort)r;
}

// ---------------------------------------------------------------------------
// K1: per-point squared norms (fp32) + transpose x (B,C,N) -> xt (B*N, C) f32
// and xb16 (B*N, C) bf16 (row-major, 256B rows) for the MFMA scorer.
// ---------------------------------------------------------------------------
__global__ __launch_bounds__(256) void k_sq_xt(const float* __restrict__ x,
                                               float* __restrict__ sq,
                                               float* __restrict__ xt,
                                               ushort* __restrict__ xb16) {
  const int b = blockIdx.x >> 6;
  const int n0 = (blockIdx.x & 63) << 6;
  __shared__ float xs[C_][65];
  const float* xb = x + (size_t)b * C_ * N_;
  for (int id = threadIdx.x; id < C_ * 64; id += 256) {
    const int c = id >> 6, n = id & 63;
    xs[c][n] = xb[(size_t)c * N_ + n0 + n];
  }
  __syncthreads();
  if (threadIdx.x < 64) {
    const int n = threadIdx.x;
    float acc = 0.f;
#pragma unroll
    for (int c = 0; c < C_; ++c) { const float v = xs[c][n]; acc = fmaf(v, v, acc); }
    sq[b * N_ + n0 + n] = acc;
  }
  const int r = threadIdx.x >> 2;
  const int p = threadIdx.x & 3;
  float* dst = xt + ((size_t)(b * N_ + n0 + r)) * C_ + p * 32;
#pragma unroll
  for (int c0 = 0; c0 < 32; c0 += 4) {
    float4 o;
    o.x = xs[p * 32 + c0 + 0][r];
    o.y = xs[p * 32 + c0 + 1][r];
    o.z = xs[p * 32 + c0 + 2][r];
    o.w = xs[p * 32 + c0 + 3][r];
    *(float4*)(dst + c0) = o;
  }
  ushort* bdst = xb16 + ((size_t)(b * N_ + n0 + r)) * C_ + p * 32;
#pragma unroll
  for (int c0 = 0; c0 < 32; c0 += 8) {
    s16x8 o;
#pragma unroll
    for (int e = 0; e < 8; ++e) o[e] = (short)f2bf(xs[p * 32 + c0 + e][r]);
    *(s16x8*)(bdst + c0) = o;
  }
}

// ---------------------------------------------------------------------------
// K2: bf16 MFMA score GEMM + branchless packed top-16 selection.
// Block = 4 waves over 64 i-rows: wave (g = w>>1, h = w&1) computes rows
// [i0+32g, i0+32g+32) x j-half [2048h, 2048h+2048), tiles of 32 j.
// MFMA 32x32x16, D[j][i]: lane l holds i = l&31, j = (r&3)+8(r>>2)+4(l>>5).
// Score biased positive (SBIAS - sq_j/2 folded into C-in) -> fp32 bits are
// order-monotone; packed u32 = (bits & 0xFFFFF000) | (4095 - j).
// Each lane keeps a sorted top-16 of its disjoint j-subset via a pure
// max/min swap chain (32 predicated VALU ops / 64 values, no branches).
// End: 4 sublists/row -> 64-lane bitonic merge -> top-24 candidates.
// Operands loaded L2-direct to registers (j-data = 1MB/batch, L2-resident);
// no LDS / barriers in the main loop.
// ---------------------------------------------------------------------------
__global__ __launch_bounds__(256, 2) void k_knn_mfma(
    const ushort* __restrict__ xb16, const float* __restrict__ sq,
    int* __restrict__ cand) {
  const int b  = blockIdx.x >> 6;
  const int i0 = (blockIdx.x & 63) << 6;
  const int t  = threadIdx.x;
  const int w  = t >> 6;
  const int lane = t & 63;
  const int g = w >> 1;         // row-group (0/1)
  const int h = w & 1;          // j-half (0/1)

  __shared__ unsigned lds_lists[64 * 64];   // [row 64][list 4][slot 16] 16KB

  const ushort* xbB = xb16 + (((size_t)b) << 12) * C_;
  const float* sqB = sq + (b << 12);
  const int ibase = i0 + (g << 5);
  const int jh0 = h << 11;

  // B-fragments (X_i, fixed): lane l -> col i = ibase+(l&31), k=(l>>5)*8+e
  s16x8 bfr[8];
  {
    const ushort* ip = xbB + ((size_t)(ibase + (lane & 31))) * C_ + (lane >> 5) * 8;
#pragma unroll
    for (int ks = 0; ks < 8; ++ks) bfr[ks] = *(const s16x8*)(ip + ks * 16);
  }

  // Per-lane sorted top-16 packed list (descending), init 0 (= -inf)
  unsigned lst[K_];
#pragma unroll
  for (int m = 0; m < K_; ++m) lst[m] = 0u;

  const ushort* aplane = xbB + (size_t)(lane & 31) * C_ + (lane >> 5) * 8;
  const float* sqlane = sqB + 4 * (lane >> 5);
  const unsigned vb2 = 4095u - 4u * (unsigned)(lane >> 5);

  s16x8 afA[8], afB[8];
  float4 sqA[4], sqB4[4];

#define LOADT(AF, SQ, J0)                                                  \
  {                                                                        \
    const ushort* ap = aplane + (size_t)(J0) * C_;                         \
    _Pragma("unroll")                                                      \
    for (int ks = 0; ks < 8; ++ks) (AF)[ks] = *(const s16x8*)(ap + ks * 16); \
    _Pragma("unroll")                                                      \
    for (int u = 0; u < 4; ++u) (SQ)[u] = *(const float4*)(sqlane + (J0) + 8 * u); \
  }

#define COMPT(AF, SQ, J0)                                                  \
  {                                                                        \
    f32x16 acc;                                                            \
    _Pragma("unroll")                                                      \
    for (int r = 0; r < 16; ++r) {                                         \
      const float sv = (r & 1) ? ((r & 2) ? (SQ)[r >> 2].w : (SQ)[r >> 2].y) \
                               : ((r & 2) ? (SQ)[r >> 2].z : (SQ)[r >> 2].x); \
      acc[r] = fmaf(sv, -0.5f, SBIAS);                                     \
    }                                                                      \
    acc = __builtin_amdgcn_mfma_f32_32x32x16_bf16((AF)[0], bfr[0], acc, 0, 0, 0); \
    _Pragma("unroll")                                                      \
    for (int ks = 1; ks < 8; ++ks)                                         \
      acc = __builtin_amdgcn_mfma_f32_32x32x16_bf16((AF)[ks], bfr[ks], acc, 0, 0, 0); \
    _Pragma("unroll")                                                      \
    for (int r = 0; r < 16; ++r) {                                         \
      const unsigned u = __float_as_uint(acc[r]);                          \
      unsigned p = (u & 0xFFFFF000u) | (vb2 - (unsigned)((J0) + (r & 3) + 8 * (r >> 2))); \
      _Pragma("unroll")                                                    \
      for (int m = 0; m < K_; ++m) {                                       \
        const unsigned mx = p > lst[m] ? p : lst[m];                       \
        const unsigned mn = p > lst[m] ? lst[m] : p;                       \
        lst[m] = mx; p = mn;                                               \
      }                                                                    \
    }                                                                      \
  }

  LOADT(afA, sqA, jh0);
  for (int jt = 0; jt < 64; jt += 2) {
    const int j0e = jh0 + jt * 32;
    LOADT(afB, sqB4, j0e + 32);
    COMPT(afA, sqA, j0e);
    if (jt + 2 < 64) LOADT(afA, sqA, j0e + 64);
    COMPT(afB, sqB4, j0e + 32);
  }

  // ---- write 4 sublists per row to LDS, then bitonic-merge to top-24 ----
  {
    const int rl = (g << 5) + (lane & 31);
    const int listid = (h << 1) + (lane >> 5);
    unsigned* dst = &lds_lists[(rl * 4 + listid) * 16];
#pragma unroll
    for (int m = 0; m < K_; ++m) dst[m] = lst[m];
  }
  __syncthreads();

  const int up = lane >> 5;
  const int ladj = up ? (lane ^ 31) : lane;
  const int run = lane >> 4;
  const int slot = (run & 1) ? (15 - (lane & 15)) : (lane & 15);
  for (int rr = 0; rr < 16; ++rr) {
    const int row = (w << 4) + rr;
    unsigned v = lds_lists[row * 64 + run * 16 + slot];
    // stage A: merge pairs of sorted-16 runs -> lanes 0-31 desc, 32-63 asc
#pragma unroll
    for (int ms = 16; ms >= 1; ms >>= 1) {
      const unsigned pv = __shfl_xor(v, ms, 64);
      const unsigned mx = v > pv ? v : pv;
      const unsigned mn = v > pv ? pv : v;
      v = ((ladj & ms) == 0) ? mx : mn;
    }
    // stage B: full 64-length bitonic -> descending
#pragma unroll
    for (int ms = 32; ms >= 1; ms >>= 1) {
      const unsigned pv = __shfl_xor(v, ms, 64);
      const unsigned mx = v > pv ? v : pv;
      const unsigned mn = v > pv ? pv : v;
      v = ((lane & ms) == 0) ? mx : mn;
    }
    if (lane < NC_) {
      const int j = 4095 - (int)(v & 0xFFFu);
      cand[((size_t)((b << 12) + i0 + row)) * NC_ + lane] = j;
    }
  }
}

// ---------------------------------------------------------------------------
// K2b: exact fp64 re-rank of the 24 candidates -> final top-16 indices.
// ---------------------------------------------------------------------------
__global__ __launch_bounds__(256) void k_refine(const float* __restrict__ xt,
                                                const int* __restrict__ cand,
                                                int* __restrict__ knn) {
  const int half = threadIdx.x >> 5;
  const int l = threadIdx.x & 31;
  const int row = blockIdx.x * 8 + half;
  const int b = row >> 12;
  const float4* xr4 = (const float4*)(xt + (size_t)row * C_);
  double d = DBL_MAX;
  int j = INT_MAX;
  if (l < NC_) {
    j = cand[(size_t)row * NC_ + l];
    const float4* xj4 = (const float4*)(xt + ((size_t)(b << 12) + j) * C_);
    double acc = 0.0;
#pragma unroll 8
    for (int c = 0; c < C_ / 4; ++c) {
      const float4 a = xr4[c];
      const float4 v = xj4[c];
      const double dx = (double)a.x - (double)v.x;
      const double dy = (double)a.y - (double)v.y;
      const double dz = (double)a.z - (double)v.z;
      const double dw = (double)a.w - (double)v.w;
      acc += dx * dx + dy * dy + dz * dz + dw * dw;
    }
    d = acc;
  }
  int* dst = knn + (size_t)row * K_;
  for (int m = 0; m < K_; ++m) {
    double bd = d; int bj = j;
#pragma unroll
    for (int off = 16; off > 0; off >>= 1) {
      const double od = __shfl_xor(bd, off, 32);
      const int oj = __shfl_xor(bj, off, 32);
      if (od < bd || (od == bd && oj < bj)) { bd = od; bj = oj; }
    }
    if (bj == j) d = DBL_MAX;
    if (l == 0) dst[m] = bj;
  }
}

// ---------------------------------------------------------------------------
// K3: gather + max-pool over 16 neighbors.
// ---------------------------------------------------------------------------
__global__ __launch_bounds__(256) void k_gather(const float* __restrict__ xt,
                                                const int* __restrict__ knn,
                                                float* __restrict__ pooled) {
  const int row = blockIdx.x * 4 + (threadIdx.x >> 6);
  const int lane = threadIdx.x & 63;
  const int b = row >> 12;
  const int* id = knn + (size_t)row * K_;
  float mx0 = -FLT_MAX, mx1 = -FLT_MAX;
#pragma unroll
  for (int m = 0; m < K_; ++m) {
    const int j = id[m];
    const float2 v = *(const float2*)&xt[((size_t)(b << 12) + j) * C_ + lane * 2];
    mx0 = fmaxf(mx0, v.x);
    mx1 = fmaxf(mx1, v.y);
  }
  float2 o; o.x = mx0; o.y = mx1;
  *(float2*)&pooled[(size_t)row * C_ + lane * 2] = o;
}

// ---------------------------------------------------------------------------
// K4: conv GEMM (stats pass) -> per-channel sum / sumsq.
// ---------------------------------------------------------------------------
__global__ __launch_bounds__(256, 2) void k_stats(const float* __restrict__ pooled,
                                                  const float* __restrict__ w,
                                                  const float* __restrict__ bias,
                                                  float* __restrict__ gsum,
                                                  float* __restrict__ gsumsq) {
  const int m0 = blockIdx.x << 6;
  __shared__ float pt[C_][68];
  __shared__ float wt[C_][36];
  __shared__ float bsum[32], bsq[32];
  const int t = threadIdx.x;
  for (int id = t; id < 64 * C_; id += 256) {
    const int row = id >> 7, c = id & 127;
    pt[c][row] = pooled[(size_t)(m0 + row) * C_ + c];
  }
  const int tx = t & 15, ty = t >> 4;
  for (int o0 = 0; o0 < OUT_; o0 += 32) {
    __syncthreads();
    for (int id = t; id < 32 * C_; id += 256) {
      const int oo = id >> 7, c = id & 127;
      wt[c][oo] = w[(size_t)(o0 + oo) * C_ + c];
    }
    if (t < 32) { bsum[t] = 0.f; bsq[t] = 0.f; }
    __syncthreads();
    float acc[4][2] = {};
#pragma unroll 8
    for (int cc = 0; cc < C_; ++cc) {
      const float4 a = *(const float4*)&pt[cc][ty * 4];
      const float2 wv = *(const float2*)&wt[cc][tx * 2];
      acc[0][0] = fmaf(a.x, wv.x, acc[0][0]);
      acc[0][1] = fmaf(a.x, wv.y, acc[0][1]);
      acc[1][0] = fmaf(a.y, wv.x, acc[1][0]);
      acc[1][1] = fmaf(a.y, wv.y, acc[1][1]);
      acc[2][0] = fmaf(a.z, wv.x, acc[2][0]);
      acc[2][1] = fmaf(a.z, wv.y, acc[2][1]);
      acc[3][0] = fmaf(a.w, wv.x, acc[3][0]);
      acc[3][1] = fmaf(a.w, wv.y, acc[3][1]);
    }
#pragma unroll
    for (int ci = 0; ci < 2; ++ci) {
      const float bi = bias[o0 + tx * 2 + ci];
      float s = 0.f, q = 0.f;
#pragma unroll
      for (int ri = 0; ri < 4; ++ri) {
        const float y = acc[ri][ci] + bi;
        s += y;
        q = fmaf(y, y, q);
      }
      atomicAdd(&bsum[tx * 2 + ci], s);
      atomicAdd(&bsq[tx * 2 + ci], q);
    }
    __syncthreads();
    if (t < 32) {
      atomicAdd(&gsum[o0 + t], bsum[t]);
      atomicAdd(&gsumsq[o0 + t], bsq[t]);
    }
  }
}

// ---------------------------------------------------------------------------
// K5: conv GEMM again + fused BN(train) + ReLU + transposed store (B,OUT,N).
// ---------------------------------------------------------------------------
__global__ __launch_bounds__(256, 2) void k_norm(const float* __restrict__ pooled,
                                                 const float* __restrict__ w,
                                                 const float* __restrict__ bias,
                                                 const float* __restrict__ gamma,
                                                 const float* __restrict__ beta,
                                                 const float* __restrict__ gsum,
                                                 const float* __restrict__ gsumsq,
                                                 float* __restrict__ out) {
  const int m0 = blockIdx.x << 6;
  const int b = m0 >> 12;
  const int n0 = m0 & (N_ - 1);
  __shared__ float pt[C_][68];
  __shared__ float wt[C_][36];
  __shared__ float sscale[32], sshift[32];
  const int t = threadIdx.x;
  for (int id = t; id < 64 * C_; id += 256) {
    const int row = id >> 7, c = id & 127;
    pt[c][row] = pooled[(size_t)(m0 + row) * C_ + c];
  }
  const int tx = t & 15, ty = t >> 4;
  const float inv = 1.f / (float)BN_;
  for (int o0 = 0; o0 < OUT_; o0 += 32) {
    __syncthreads();
    for (int id = t; id < 32 * C_; id += 256) {
      const int oo = id >> 7, c = id & 127;
      wt[c][oo] = w[(size_t)(o0 + oo) * C_ + c];
    }
    if (t < 32) {
      const int o = o0 + t;
      const float mean = gsum[o] * inv;
      const float var = gsumsq[o] * inv - mean * mean;
      const float sc = gamma[o] / sqrtf(var + 1e-5f);
      sscale[t] = sc;
      sshift[t] = (bias[o] - mean) * sc + beta[o];
    }
    __syncthreads();
    float acc[4][2] = {};
#pragma unroll 8
    for (int cc = 0; cc < C_; ++cc) {
      const float4 a = *(const float4*)&pt[cc][ty * 4];
      const float2 wv = *(const float2*)&wt[cc][tx * 2];
      acc[0][0] = fmaf(a.x, wv.x, acc[0][0]);
      acc[0][1] = fmaf(a.x, wv.y, acc[0][1]);
      acc[1][0] = fmaf(a.y, wv.x, acc[1][0]);
      acc[1][1] = fmaf(a.y, wv.y, acc[1][1]);
      acc[2][0] = fmaf(a.z, wv.x, acc[2][0]);
      acc[2][1] = fmaf(a.z, wv.y, acc[2][1]);
      acc[3][0] = fmaf(a.w, wv.x, acc[3][0]);
      acc[3][1] = fmaf(a.w, wv.y, acc[3][1]);
    }
#pragma unroll
    for (int ci = 0; ci < 2; ++ci) {
      const int o = o0 + tx * 2 + ci;
      const float scl = sscale[tx * 2 + ci];
      const float sh = sshift[tx * 2 + ci];
      float4 r;
      r.x = fmaxf(fmaf(acc[0][ci], scl, sh), 0.f);
      r.y = fmaxf(fmaf(acc[1][ci], scl, sh), 0.f);
      r.z = fmaxf(fmaf(acc[2][ci], scl, sh), 0.f);
      r.w = fmaxf(fmaf(acc[3][ci], scl, sh), 0.f);
      *(float4*)&out[((size_t)(b * OUT_ + o)) * N_ + n0 + ty * 4] = r;
    }
  }
}

// ---------------------------------------------------------------------------
// Launcher. ws layout (floats):
//   sq[32768] | xt[32768*128] | knn(int) | cand(int) | pooled | gsum | gsumsq
//   | xb16[32768*128] bf16   (~45.5 MB total)
// ---------------------------------------------------------------------------
extern "C" void kernel_launch(void* const* d_in, const int* in_sizes, int n_in,
                              void* d_out, int out_size, void* d_ws, size_t ws_size,
                              hipStream_t stream) {
  const float* x      = (const float*)d_in[0];
  const float* conv_w = (const float*)d_in[1];
  const float* conv_b = (const float*)d_in[2];
  const float* gamma  = (const float*)d_in[3];
  const float* beta   = (const float*)d_in[4];
  float* out = (float*)d_out;

  float* ws = (float*)d_ws;
  float* sq = ws;                                        // 32768
  float* xt = sq + BN_;                                  // 4194304
  int*   knn = (int*)(xt + (size_t)BN_ * C_);            // 524288
  int*   cand = knn + (size_t)BN_ * K_;                  // 786432
  float* pooled = (float*)(cand + (size_t)BN_ * NC_);    // 4194304
  float* gsum = pooled + (size_t)BN_ * C_;               // 256
  float* gsumsq = gsum + OUT_;                           // 256
  ushort* xb16 = (ushort*)(gsumsq + OUT_);               // 4194304 bf16

  hipMemsetAsync(gsum, 0, 2 * OUT_ * sizeof(float), stream);

  k_sq_xt<<<B_ * (N_ / 64), 256, 0, stream>>>(x, sq, xt, xb16);
  k_knn_mfma<<<B_ * (N_ / 64), 256, 0, stream>>>(xb16, sq, cand);
  k_refine<<<BN_ / 8, 256, 0, stream>>>(xt, cand, knn);
  k_gather<<<BN_ / 4, 256, 0, stream>>>(xt, knn, pooled);
  k_stats<<<BN_ / 64, 256, 0, stream>>>(pooled, conv_w, conv_b, gsum, gsumsq);
  k_norm<<<BN_ / 64, 256, 0, stream>>>(pooled, conv_w, conv_b, gamma, beta,
                                       gsum, gsumsq, out);
}

// Round 7
// 348.253 us; speedup vs baseline: 7.0634x; 1.2675x over previous
//
#include <hip/hip_runtime.h>
#include <cfloat>
#include <climits>
#include <cstdint>

// Problem constants
#define B_ 8
#define C_ 128
#define N_ 4096
#define OUT_ 256
#define K_ 16
#define NC_ 24          // candidate margin for exact fp64 re-rank
#define BN_ (B_ * N_)   // 32768
#define SBIAS 200.0f    // score bias keeps packed scores positive

typedef __attribute__((ext_vector_type(8))) short s16x8;
typedef __attribute__((ext_vector_type(16))) float f32x16;

static __device__ __forceinline__ ushort f2bf(float f) {
  uint32_t u = __float_as_uint(f);
  uint32_t r = (u + 0x7fffu + ((u >> 16) & 1u)) >> 16;
  return (ushort)r;
}
static __device__ __forceinline__ float bf2f(ushort u) {
  return __uint_as_float(((uint32_t)u) << 16);
}

// ---------------------------------------------------------------------------
// K1: squared norms + transpose x -> xt (B*N, C) f32 and xb16 bf16 rows.
// ---------------------------------------------------------------------------
__global__ __launch_bounds__(256) void k_sq_xt(const float* __restrict__ x,
                                               float* __restrict__ sq,
                                               float* __restrict__ xt,
                                               ushort* __restrict__ xb16) {
  const int b = blockIdx.x >> 6;
  const int n0 = (blockIdx.x & 63) << 6;
  __shared__ float xs[C_][65];
  const float* xb = x + (size_t)b * C_ * N_;
  for (int id = threadIdx.x; id < C_ * 64; id += 256) {
    const int c = id >> 6, n = id & 63;
    xs[c][n] = xb[(size_t)c * N_ + n0 + n];
  }
  __syncthreads();
  if (threadIdx.x < 64) {
    const int n = threadIdx.x;
    float acc = 0.f;
#pragma unroll
    for (int c = 0; c < C_; ++c) { const float v = xs[c][n]; acc = fmaf(v, v, acc); }
    sq[b * N_ + n0 + n] = acc;
  }
  const int r = threadIdx.x >> 2;
  const int p = threadIdx.x & 3;
  float* dst = xt + ((size_t)(b * N_ + n0 + r)) * C_ + p * 32;
#pragma unroll
  for (int c0 = 0; c0 < 32; c0 += 4) {
    float4 o;
    o.x = xs[p * 32 + c0 + 0][r];
    o.y = xs[p * 32 + c0 + 1][r];
    o.z = xs[p * 32 + c0 + 2][r];
    o.w = xs[p * 32 + c0 + 3][r];
    *(float4*)(dst + c0) = o;
  }
  ushort* bdst = xb16 + ((size_t)(b * N_ + n0 + r)) * C_ + p * 32;
#pragma unroll
  for (int c0 = 0; c0 < 32; c0 += 8) {
    s16x8 o;
#pragma unroll
    for (int e = 0; e < 8; ++e) o[e] = (short)f2bf(xs[p * 32 + c0 + e][r]);
    *(s16x8*)(bdst + c0) = o;
  }
}

// ---------------------------------------------------------------------------
// K1b: weights fp32 -> bf16.
// ---------------------------------------------------------------------------
__global__ __launch_bounds__(256) void k_wprep(const float* __restrict__ w,
                                               ushort* __restrict__ wb16) {
  const int i = blockIdx.x * 256 + threadIdx.x;   // grid 128 -> 32768
  wb16[i] = f2bf(w[i]);
}

// ---------------------------------------------------------------------------
// K2: bf16 MFMA score GEMM + branchless packed top-16 selection.
// EXACT byte-for-byte revert to the round-3 kernel that PASSED (169 us):
// per-value sorted swap-chain insertion (no sorting network).
// ---------------------------------------------------------------------------
__global__ __launch_bounds__(256, 2) void k_knn_mfma(
    const ushort* __restrict__ xb16, const float* __restrict__ sq,
    int* __restrict__ cand) {
  const int b  = blockIdx.x >> 6;
  const int i0 = (blockIdx.x & 63) << 6;
  const int t  = threadIdx.x;
  const int w  = t >> 6;
  const int lane = t & 63;
  const int g = w >> 1;         // row-group (0/1)
  const int h = w & 1;          // j-half (0/1)

  __shared__ unsigned lds_lists[64 * 64];   // 16KB

  const ushort* xbB = xb16 + (((size_t)b) << 12) * C_;
  const float* sqB = sq + (b << 12);
  const int ibase = i0 + (g << 5);
  const int jh0 = h << 11;

  s16x8 bfr[8];
  {
    const ushort* ip = xbB + ((size_t)(ibase + (lane & 31))) * C_ + (lane >> 5) * 8;
#pragma unroll
    for (int ks = 0; ks < 8; ++ks) bfr[ks] = *(const s16x8*)(ip + ks * 16);
  }

  unsigned lst[K_];
#pragma unroll
  for (int m = 0; m < K_; ++m) lst[m] = 0u;

  const ushort* aplane = xbB + (size_t)(lane & 31) * C_ + (lane >> 5) * 8;
  const float* sqlane = sqB + 4 * (lane >> 5);
  const unsigned vb2 = 4095u - 4u * (unsigned)(lane >> 5);

  s16x8 afA[8], afB[8];
  float4 sqA[4], sqB4[4];

#define LOADT(AF, SQ, J0)                                                  \
  {                                                                        \
    const ushort* ap = aplane + (size_t)(J0) * C_;                         \
    _Pragma("unroll")                                                      \
    for (int ks = 0; ks < 8; ++ks) (AF)[ks] = *(const s16x8*)(ap + ks * 16); \
    _Pragma("unroll")                                                      \
    for (int u = 0; u < 4; ++u) (SQ)[u] = *(const float4*)(sqlane + (J0) + 8 * u); \
  }

#define COMPT(AF, SQ, J0)                                                  \
  {                                                                        \
    f32x16 acc;                                                            \
    _Pragma("unroll")                                                      \
    for (int r = 0; r < 16; ++r) {                                         \
      const float sv = (r & 1) ? ((r & 2) ? (SQ)[r >> 2].w : (SQ)[r >> 2].y) \
                               : ((r & 2) ? (SQ)[r >> 2].z : (SQ)[r >> 2].x); \
      acc[r] = fmaf(sv, -0.5f, SBIAS);                                     \
    }                                                                      \
    acc = __builtin_amdgcn_mfma_f32_32x32x16_bf16((AF)[0], bfr[0], acc, 0, 0, 0); \
    _Pragma("unroll")                                                      \
    for (int ks = 1; ks < 8; ++ks)                                         \
      acc = __builtin_amdgcn_mfma_f32_32x32x16_bf16((AF)[ks], bfr[ks], acc, 0, 0, 0); \
    _Pragma("unroll")                                                      \
    for (int r = 0; r < 16; ++r) {                                         \
      const unsigned u = __float_as_uint(acc[r]);                          \
      unsigned p = (u & 0xFFFFF000u) | (vb2 - (unsigned)((J0) + (r & 3) + 8 * (r >> 2))); \
      _Pragma("unroll")                                                    \
      for (int m = 0; m < K_; ++m) {                                       \
        const unsigned mx = p > lst[m] ? p : lst[m];                       \
        const unsigned mn = p > lst[m] ? lst[m] : p;                       \
        lst[m] = mx; p = mn;                                               \
      }                                                                    \
    }                                                                      \
  }

  LOADT(afA, sqA, jh0);
  for (int jt = 0; jt < 64; jt += 2) {
    const int j0e = jh0 + jt * 32;
    LOADT(afB, sqB4, j0e + 32);
    COMPT(afA, sqA, j0e);
    if (jt + 2 < 64) LOADT(afA, sqA, j0e + 64);
    COMPT(afB, sqB4, j0e + 32);
  }

  // ---- write 4 sublists per row to LDS, then bitonic-merge to top-24 ----
  {
    const int rl = (g << 5) + (lane & 31);
    const int listid = (h << 1) + (lane >> 5);
    unsigned* dst = &lds_lists[(rl * 4 + listid) * 16];
#pragma unroll
    for (int m = 0; m < K_; ++m) dst[m] = lst[m];
  }
  __syncthreads();

  const int up = lane >> 5;
  const int ladj = up ? (lane ^ 31) : lane;
  const int run = lane >> 4;
  const int slot = (run & 1) ? (15 - (lane & 15)) : (lane & 15);
  for (int rr = 0; rr < 16; ++rr) {
    const int row = (w << 4) + rr;
    unsigned v = lds_lists[row * 64 + run * 16 + slot];
    // stage A: merge pairs of sorted-16 runs -> lanes 0-31 desc, 32-63 asc
#pragma unroll
    for (int ms = 16; ms >= 1; ms >>= 1) {
      const unsigned pv = __shfl_xor(v, ms, 64);
      const unsigned mx = v > pv ? v : pv;
      const unsigned mn = v > pv ? pv : v;
      v = ((ladj & ms) == 0) ? mx : mn;
    }
    // stage B: full 64-length bitonic -> descending
#pragma unroll
    for (int ms = 32; ms >= 1; ms >>= 1) {
      const unsigned pv = __shfl_xor(v, ms, 64);
      const unsigned mx = v > pv ? v : pv;
      const unsigned mn = v > pv ? pv : v;
      v = ((lane & ms) == 0) ? mx : mn;
    }
    if (lane < NC_) {
      const int j = 4095 - (int)(v & 0xFFFu);
      cand[((size_t)((b << 12) + i0 + row)) * NC_ + lane] = j;
    }
  }
}

// ---------------------------------------------------------------------------
// K3: exact fp64 re-rank of 24 candidates -> top-16, fused gather+max-pool,
// emits pooled bf16 rows. Half-wave (32 lanes) per point row.
// ---------------------------------------------------------------------------
__global__ __launch_bounds__(256) void k_refine_gather(
    const float* __restrict__ xt, const int* __restrict__ cand,
    ushort* __restrict__ pooled16) {
  const int half = threadIdx.x >> 5;
  const int l = threadIdx.x & 31;
  const int row = blockIdx.x * 8 + half;
  const int b = row >> 12;
  const size_t bbase = (size_t)(b << 12);
  const float4* xr4 = (const float4*)(xt + (size_t)row * C_);
  double d = DBL_MAX;
  int j = INT_MAX;
  if (l < NC_) {
    j = cand[(size_t)row * NC_ + l];
    const float4* xj4 = (const float4*)(xt + (bbase + j) * C_);
    double acc = 0.0;
#pragma unroll 8
    for (int c = 0; c < C_ / 4; ++c) {
      const float4 a = xr4[c];
      const float4 v = xj4[c];
      const double dx = (double)a.x - (double)v.x;
      const double dy = (double)a.y - (double)v.y;
      const double dz = (double)a.z - (double)v.z;
      const double dw = (double)a.w - (double)v.w;
      acc += dx * dx + dy * dy + dz * dz + dw * dw;
    }
    d = acc;
  }
  int win[K_];
#pragma unroll
  for (int m = 0; m < K_; ++m) {
    double bd = d; int bj = j;
#pragma unroll
    for (int off = 16; off > 0; off >>= 1) {
      const double od = __shfl_xor(bd, off, 32);
      const int oj = __shfl_xor(bj, off, 32);
      if (od < bd || (od == bd && oj < bj)) { bd = od; bj = oj; }
    }
    win[m] = bj;
    if (bj == j) d = DBL_MAX;
  }
  const int c0 = l * 4;
  float4 mx = make_float4(-FLT_MAX, -FLT_MAX, -FLT_MAX, -FLT_MAX);
#pragma unroll
  for (int m = 0; m < K_; ++m) {
    const float4 v = *(const float4*)(xt + (bbase + win[m]) * C_ + c0);
    mx.x = fmaxf(mx.x, v.x);
    mx.y = fmaxf(mx.y, v.y);
    mx.z = fmaxf(mx.z, v.z);
    mx.w = fmaxf(mx.w, v.w);
  }
  ushort4 o;
  o.x = f2bf(mx.x); o.y = f2bf(mx.y); o.z = f2bf(mx.z); o.w = f2bf(mx.w);
  *(ushort4*)(pooled16 + (size_t)row * C_ + c0) = o;
}

// ---------------------------------------------------------------------------
// K4: bf16 MFMA conv + bias -> y bf16, layout (B,OUT,N).
// ---------------------------------------------------------------------------
__global__ __launch_bounds__(256) void k_conv_y(const ushort* __restrict__ pooled16,
                                                const ushort* __restrict__ wb16,
                                                const float* __restrict__ bias,
                                                ushort* __restrict__ y16) {
  const int i0 = blockIdx.x << 7;
  const int b = i0 >> 12;
  const int nb = i0 & (N_ - 1);
  const int t = threadIdx.x, w = t >> 6, l = t & 63;
  __shared__ float biasl[OUT_];
  biasl[t] = bias[t];
  __syncthreads();
  const int kh = l >> 5;
  const int irow = i0 + (w << 5) + (l & 31);
  s16x8 pf[8];
  {
    const ushort* pp = pooled16 + (size_t)irow * C_ + kh * 8;
#pragma unroll
    for (int ks = 0; ks < 8; ++ks) pf[ks] = *(const s16x8*)(pp + ks * 16);
  }
  const int nout = nb + (w << 5) + (l & 31);
  for (int ot = 0; ot < 8; ++ot) {
    const ushort* wp = wb16 + (size_t)(ot * 32 + (l & 31)) * C_ + kh * 8;
    s16x8 wf[8];
#pragma unroll
    for (int ks = 0; ks < 8; ++ks) wf[ks] = *(const s16x8*)(wp + ks * 16);
    f32x16 acc;
#pragma unroll
    for (int r = 0; r < 16; ++r) acc[r] = 0.f;
#pragma unroll
    for (int ks = 0; ks < 8; ++ks)
      acc = __builtin_amdgcn_mfma_f32_32x32x16_bf16(wf[ks], pf[ks], acc, 0, 0, 0);
#pragma unroll
    for (int r = 0; r < 16; ++r) {
      const int o = ot * 32 + (r & 3) + 8 * (r >> 2) + 4 * kh;
      const float y = acc[r] + biasl[o];
      y16[((size_t)(b * OUT_ + o) << 12) + nout] = f2bf(y);
    }
  }
}

// ---------------------------------------------------------------------------
// K5: per-channel BN stats from the STORED y (self-consistent by design).
// ---------------------------------------------------------------------------
__global__ __launch_bounds__(256) void k_ystats(const ushort* __restrict__ y16,
                                                const float* __restrict__ gamma,
                                                const float* __restrict__ beta,
                                                float2* __restrict__ ss) {
  const int o = blockIdx.x;
  const int t = threadIdx.x;
  float s1 = 0.f, s2 = 0.f;
  for (int b = 0; b < B_; ++b) {
    const ushort* yp = y16 + ((size_t)(b * OUT_ + o) << 12);
#pragma unroll
    for (int it = 0; it < 2; ++it) {
      const s16x8 v = *(const s16x8*)(yp + (it * 256 + t) * 8);
#pragma unroll
      for (int e = 0; e < 8; ++e) {
        const float f = bf2f((ushort)v[e]);
        s1 += f;
        s2 = fmaf(f, f, s2);
      }
    }
  }
#pragma unroll
  for (int off = 32; off > 0; off >>= 1) {
    s1 += __shfl_xor(s1, off, 64);
    s2 += __shfl_xor(s2, off, 64);
  }
  __shared__ float r1[4], r2[4];
  if ((t & 63) == 0) { r1[t >> 6] = s1; r2[t >> 6] = s2; }
  __syncthreads();
  if (t == 0) {
    const float S1 = r1[0] + r1[1] + r1[2] + r1[3];
    const float S2 = r2[0] + r2[1] + r2[2] + r2[3];
    const float inv = 1.f / (float)BN_;
    const float mean = S1 * inv;
    const float var = S2 * inv - mean * mean;
    const float scale = gamma[o] / sqrtf(var + 1e-5f);
    float2 r; r.x = scale; r.y = beta[o] - mean * scale;
    ss[o] = r;
  }
}

// ---------------------------------------------------------------------------
// K6: elementwise BN apply + ReLU: out = max(y*scale + shift, 0), fp32 out.
// ---------------------------------------------------------------------------
__global__ __launch_bounds__(256) void k_bn(const ushort* __restrict__ y16,
                                            const float2* __restrict__ ss,
                                            float* __restrict__ out) {
  const size_t idx = ((size_t)blockIdx.x * 256 + threadIdx.x) * 4;
  const int o = (int)((idx >> 12) & (OUT_ - 1));
  const float2 sv = ss[o];
  const ushort4 v = *(const ushort4*)(y16 + idx);
  float4 r;
  r.x = fmaxf(fmaf(bf2f(v.x), sv.x, sv.y), 0.f);
  r.y = fmaxf(fmaf(bf2f(v.y), sv.x, sv.y), 0.f);
  r.z = fmaxf(fmaf(bf2f(v.z), sv.x, sv.y), 0.f);
  r.w = fmaxf(fmaf(bf2f(v.w), sv.x, sv.y), 0.f);
  *(float4*)(out + idx) = r;
}

// ---------------------------------------------------------------------------
// Launcher. ws layout:
//   sq f32[32768] | xt f32[4194304] (aliased by y16 bf16[8388608] after K3)
//   | cand i32[786432] | pooled16 u16[4194304] | xb16 u16[4194304]
//   | wb16 u16[32768] | ss float2[256]       total ≈ 35.4 MB
// ---------------------------------------------------------------------------
extern "C" void kernel_launch(void* const* d_in, const int* in_sizes, int n_in,
                              void* d_out, int out_size, void* d_ws, size_t ws_size,
                              hipStream_t stream) {
  const float* x      = (const float*)d_in[0];
  const float* conv_w = (const float*)d_in[1];
  const float* conv_b = (const float*)d_in[2];
  const float* gamma  = (const float*)d_in[3];
  const float* beta   = (const float*)d_in[4];
  float* out = (float*)d_out;

  float* ws = (float*)d_ws;
  float* sq = ws;                                           // 32768 f32
  float* xt = sq + BN_;                                     // 4194304 f32
  ushort* y16 = (ushort*)xt;                                // alias: 8388608 bf16 (exact fit)
  int*   cand = (int*)(xt + (size_t)BN_ * C_);              // 786432 i32
  ushort* pooled16 = (ushort*)(cand + (size_t)BN_ * NC_);   // 4194304 u16
  ushort* xb16 = pooled16 + (size_t)BN_ * C_;               // 4194304 u16
  ushort* wb16 = xb16 + (size_t)BN_ * C_;                   // 32768 u16
  float2* ss = (float2*)(wb16 + (size_t)OUT_ * C_);         // 256 float2

  k_sq_xt<<<B_ * (N_ / 64), 256, 0, stream>>>(x, sq, xt, xb16);
  k_wprep<<<(OUT_ * C_) / 256, 256, 0, stream>>>(conv_w, wb16);
  k_knn_mfma<<<B_ * (N_ / 64), 256, 0, stream>>>(xb16, sq, cand);
  k_refine_gather<<<BN_ / 8, 256, 0, stream>>>(xt, cand, pooled16);
  k_conv_y<<<BN_ / 128, 256, 0, stream>>>(pooled16, wb16, conv_b, y16);
  k_ystats<<<OUT_, 256, 0, stream>>>(y16, gamma, beta, ss);
  k_bn<<<(BN_ * OUT_ / 4) / 256, 256, 0, stream>>>(y16, ss, out);
}